// Round 6
// baseline (562.208 us; speedup 1.0000x reference)
//
#include <hip/hip_runtime.h>

// ---------- types ----------
typedef __attribute__((ext_vector_type(8))) __bf16 bf16x8;
typedef __attribute__((ext_vector_type(4))) float f32x4;
typedef unsigned short u16;

__device__ __forceinline__ u16 f2bf(float f) {
    union { float f; unsigned u; } v; v.f = f;
    unsigned r = v.u + 0x7FFFu + ((v.u >> 16) & 1u);
    return (u16)(r >> 16);
}
__device__ __forceinline__ float bf2f(u16 h) {
    union { unsigned u; float f; } v; v.u = ((unsigned)h) << 16;
    return v.f;
}
// native cast: single v_cvt_pk_bf16_f32 (RNE), vs 4 VALU ops for manual round
__device__ __forceinline__ u16 f2bf_n(float f) {
    union { __bf16 b; u16 u; } t; t.b = (__bf16)f; return t.u;
}
__device__ __forceinline__ bf16x8 ld_bf16x8(const u16* p) {
    union { uint4 u; bf16x8 b; } t;
    t.u = *(const uint4*)p;
    return t.b;
}
__device__ __forceinline__ void async16(const void* g, const void* l) {
    __builtin_amdgcn_global_load_lds((const __attribute__((address_space(1))) void*)g,
                                     (__attribute__((address_space(3))) void*)l, 16, 0, 0);
}

// ---------- problem constants ----------
#define BATCH 4
#define NSEQ 2048
#define HEADS 16
#define DH 64
#define DMODEL 1024
#define MROWS 8192   // B*N
#define NQKV 3072

// ---------- elementwise ----------
__global__ void split_bf16(const float* __restrict__ src, u16* __restrict__ hi,
                           u16* __restrict__ lo, int n) {
    int i = blockIdx.x * blockDim.x + threadIdx.x;
    if (i < n) {
        float f = src[i];
        u16 h = f2bf(f);
        hi[i] = h;
        lo[i] = f2bf(f - bf2f(h));
    }
}
__global__ void cvt_bf16(const float* __restrict__ src, u16* __restrict__ dst, int n) {
    int i = blockIdx.x * blockDim.x + threadIdx.x;
    if (i < n) dst[i] = f2bf(src[i]);
}

// ---------- QKV GEMM: C[m,n] = sum_k A[m,k]*(Bh+Bl)[n,k] + bias[n], bf16 out ----------
__global__ __launch_bounds__(256) void qkv_gemm(
    const u16* __restrict__ A,
    const u16* __restrict__ Bh, const u16* __restrict__ Bl,
    const float* __restrict__ bias, u16* __restrict__ C) {
    const int K = DMODEL, N = NQKV, TK = 32;
    __shared__ __align__(16) u16 sA[128 * 32];
    __shared__ __align__(16) u16 sBh[128 * 32], sBl[128 * 32];
    const int tid = threadIdx.x, wave = tid >> 6, lane = tid & 63;
    const int quad = lane >> 4, l16 = lane & 15;
    const int m0 = blockIdx.x * 128, n0 = blockIdx.y * 128;
    const int wm = (wave & 1) * 64, wn = (wave >> 1) * 64;
    f32x4 acc[4][4] = {};

    for (int k0 = 0; k0 < K; k0 += TK) {
        __syncthreads();
        #pragma unroll
        for (int pass = 0; pass < 2; ++pass) {
            const int c = pass * 256 + tid;
            const int row = c >> 2, part = c & 3;
            const int ldsOff = (pass * 256 + wave * 64) * 16;  // bytes; dest = base + lane*16
            const size_t ga = (size_t)(m0 + row) * K + k0 + part * 8;
            const size_t gb = (size_t)(n0 + row) * K + k0 + part * 8;
            async16(A + ga, (const char*)sA + ldsOff);
            async16(Bh + gb, (const char*)sBh + ldsOff);
            async16(Bl + gb, (const char*)sBl + ldsOff);
        }
        __syncthreads();
        bf16x8 a[4];
        #pragma unroll
        for (int mt = 0; mt < 4; ++mt)
            a[mt] = ld_bf16x8(&sA[(wm + mt * 16 + l16) * TK + quad * 8]);
        #pragma unroll
        for (int nt = 0; nt < 4; ++nt) {
            const int cix = wn + nt * 16 + l16;
            bf16x8 bh = ld_bf16x8(&sBh[cix * TK + quad * 8]);
            bf16x8 bl = ld_bf16x8(&sBl[cix * TK + quad * 8]);
            #pragma unroll
            for (int mt = 0; mt < 4; ++mt) {
                acc[mt][nt] = __builtin_amdgcn_mfma_f32_16x16x32_bf16(a[mt], bh, acc[mt][nt], 0, 0, 0);
                acc[mt][nt] = __builtin_amdgcn_mfma_f32_16x16x32_bf16(a[mt], bl, acc[mt][nt], 0, 0, 0);
            }
        }
    }
    #pragma unroll
    for (int nt = 0; nt < 4; ++nt) {
        const int n = n0 + wn + nt * 16 + l16;
        const float bv = bias[n];
        #pragma unroll
        for (int mt = 0; mt < 4; ++mt) {
            const int mbase = m0 + wm + mt * 16 + quad * 4;
            #pragma unroll
            for (int r = 0; r < 4; ++r)
                C[(size_t)(mbase + r) * N + n] = f2bf_n(acc[mt][nt][r] + bv);
        }
    }
}

// ---------- out-proj GEMM: C[m,n] = sum_k A[m,k]*B[n,k], fp32 out ----------
__global__ __launch_bounds__(256) void out_gemm(
    const u16* __restrict__ A, const u16* __restrict__ B, float* __restrict__ C) {
    const int K = DMODEL, N = DMODEL, TK = 32;
    __shared__ __align__(16) u16 sA[128 * 32], sB[128 * 32];
    const int tid = threadIdx.x, wave = tid >> 6, lane = tid & 63;
    const int quad = lane >> 4, l16 = lane & 15;
    const int m0 = blockIdx.x * 128, n0 = blockIdx.y * 128;
    const int wm = (wave & 1) * 64, wn = (wave >> 1) * 64;
    f32x4 acc[4][4] = {};

    for (int k0 = 0; k0 < K; k0 += TK) {
        __syncthreads();
        #pragma unroll
        for (int pass = 0; pass < 2; ++pass) {
            const int c = pass * 256 + tid;
            const int row = c >> 2, part = c & 3;
            const int ldsOff = (pass * 256 + wave * 64) * 16;
            const size_t ga = (size_t)(m0 + row) * K + k0 + part * 8;
            const size_t gb = (size_t)(n0 + row) * K + k0 + part * 8;
            async16(A + ga, (const char*)sA + ldsOff);
            async16(B + gb, (const char*)sB + ldsOff);
        }
        __syncthreads();
        bf16x8 a[4];
        #pragma unroll
        for (int mt = 0; mt < 4; ++mt)
            a[mt] = ld_bf16x8(&sA[(wm + mt * 16 + l16) * TK + quad * 8]);
        #pragma unroll
        for (int nt = 0; nt < 4; ++nt) {
            bf16x8 b = ld_bf16x8(&sB[(wn + nt * 16 + l16) * TK + quad * 8]);
            #pragma unroll
            for (int mt = 0; mt < 4; ++mt)
                acc[mt][nt] = __builtin_amdgcn_mfma_f32_16x16x32_bf16(a[mt], b, acc[mt][nt], 0, 0, 0);
        }
    }
    #pragma unroll
    for (int nt = 0; nt < 4; ++nt) {
        const int n = n0 + wn + nt * 16 + l16;
        #pragma unroll
        for (int mt = 0; mt < 4; ++mt) {
            const int mbase = m0 + wm + mt * 16 + quad * 4;
            #pragma unroll
            for (int r = 0; r < 4; ++r)
                C[(size_t)(mbase + r) * N + n] = acc[mt][nt][r];
        }
    }
}

// ---------- l2-normalize q,k; pack to [B,H,N,DH] bf16 ----------
__global__ __launch_bounds__(256) void normalize_qk(
    const u16* __restrict__ QKV, u16* __restrict__ Qn, u16* __restrict__ Kn) {
    int wid = blockIdx.x * 4 + (threadIdx.x >> 6);  // row id = bh*N + n
    int lane = threadIdx.x & 63;                    // = d
    int n = wid & (NSEQ - 1);
    int bh = wid >> 11;
    int h = bh & (HEADS - 1), b = bh >> 4;
    size_t base = ((size_t)(b * NSEQ + n)) * NQKV + h * DH + lane;
    float q = bf2f(QKV[base]);
    float k = bf2f(QKV[base + 1024]);
    float sq = q * q, sk = k * k;
    #pragma unroll
    for (int off = 32; off >= 1; off >>= 1) {
        sq += __shfl_xor(sq, off);
        sk += __shfl_xor(sk, off);
    }
    float iq = 1.f / fmaxf(sqrtf(sq), 1e-12f);
    float ik = 1.f / fmaxf(sqrtf(sk), 1e-12f);
    size_t o = (size_t)wid * DH + lane;
    Qn[o] = f2bf(q * iq);
    Kn[o] = f2bf(k * ik);
}

// ---------- V transpose: qkv[...,v] -> Vt[B,H,DH,N] bf16 ----------
__global__ __launch_bounds__(256) void transpose_v(
    const u16* __restrict__ QKV, u16* __restrict__ Vt) {
    const int bh = blockIdx.x;
    const int n0 = blockIdx.y * 64;
    const int h = bh & (HEADS - 1), b = bh >> 4;
    __shared__ __align__(16) u16 T[64][72];
    const int tid = threadIdx.x;
    const u16* src = QKV + ((size_t)(b * NSEQ + n0)) * NQKV + 2048 + h * DH;
    #pragma unroll
    for (int c = tid; c < 512; c += 256) {
        int n = c >> 3, part = c & 7;
        *(uint4*)&T[n][part * 8] = *(const uint4*)(src + (size_t)n * NQKV + part * 8);
    }
    __syncthreads();
    u16* dst = Vt + ((size_t)bh * DH) * NSEQ + n0;
    #pragma unroll
    for (int c = tid; c < 512; c += 256) {
        int d = c >> 3, part = c & 7;
        u16 tmp[8];
        #pragma unroll
        for (int j = 0; j < 8; ++j) tmp[j] = T[part * 8 + j][d];
        *(uint4*)(dst + (size_t)d * NSEQ + part * 8) = *(const uint4*)tmp;
    }
}

// ---------- flash attention, cosine specialization + register-prefetch pipeline ----------
// R3 structure (1 tile/wave, high block count — R4 showed occupancy >> per-wave ILP).
// New: K/V global loads for tile kt+64 are issued right after the staging barrier and
// consumed at the NEXT iteration's ds_write, so L2 latency overlaps the compute phase.
__global__ __launch_bounds__(256) void flash_attn(
    const u16* __restrict__ Q, const u16* __restrict__ Kn, const u16* __restrict__ Vt,
    const float* __restrict__ lsc, u16* __restrict__ AO) {
    const int bh = blockIdx.x;
    const int q0 = blockIdx.y * 64;
    const int h = bh & (HEADS - 1), b = bh >> 4;
    const int tid = threadIdx.x, wave = tid >> 6, lane = tid & 63;
    const int quad = lane >> 4, l16 = lane & 15;
    const float scale = __expf(fminf(lsc[h], 4.6051702f));  // ln(100); here = 10
    const float c1 = scale * 1.4426950408889634f;           // scale*log2(e)

    __shared__ __align__(16) u16 Ks[64][72];      // [key][d]
    __shared__ __align__(16) u16 Vs[64][72];      // [d][key]
    __shared__ __align__(16) u16 Ps[4][16][68];   // per-wave P round-trip (C->A layout)

    const u16* qbase = Q + ((size_t)bh * NSEQ + q0 + wave * 16) * DH;
    bf16x8 qa[2];
    qa[0] = ld_bf16x8(qbase + l16 * DH + quad * 8);
    qa[1] = ld_bf16x8(qbase + l16 * DH + 32 + quad * 8);

    f32x4 O[4] = {};
    float lr[4] = {0.f, 0.f, 0.f, 0.f};

    const u16* kb = Kn + (size_t)bh * NSEQ * DH;
    const u16* vb = Vt + (size_t)bh * DH * NSEQ;

    // prefetch tile 0 into registers
    uint4 kreg[2], vreg[2];
    #pragma unroll
    for (int i = 0; i < 2; ++i) {
        int c = i * 256 + tid;
        int row = c >> 3, part = c & 7;
        kreg[i] = *(const uint4*)(kb + (size_t)row * DH + part * 8);
        vreg[i] = *(const uint4*)(vb + (size_t)row * NSEQ + part * 8);
    }

    for (int kt = 0; kt < NSEQ; kt += 64) {
        __syncthreads();  // protect LDS from previous iteration's readers
        #pragma unroll
        for (int i = 0; i < 2; ++i) {
            int c = i * 256 + tid;
            int row = c >> 3, part = c & 7;
            *(uint4*)&Ks[row][part * 8] = kreg[i];
            *(uint4*)&Vs[row][part * 8] = vreg[i];
        }
        __syncthreads();
        // issue next tile's loads now; they land during compute below
        if (kt + 64 < NSEQ) {
            #pragma unroll
            for (int i = 0; i < 2; ++i) {
                int c = i * 256 + tid;
                int row = c >> 3, part = c & 7;
                kreg[i] = *(const uint4*)(kb + (size_t)(kt + 64 + row) * DH + part * 8);
                vreg[i] = *(const uint4*)(vb + (size_t)row * NSEQ + kt + 64 + part * 8);
            }
        }

        f32x4 S[4] = {};
        #pragma unroll
        for (int nt = 0; nt < 4; ++nt) {
            bf16x8 k0 = ld_bf16x8(&Ks[nt * 16 + l16][quad * 8]);
            bf16x8 k1 = ld_bf16x8(&Ks[nt * 16 + l16][32 + quad * 8]);
            S[nt] = __builtin_amdgcn_mfma_f32_16x16x32_bf16(qa[0], k0, S[nt], 0, 0, 0);
            S[nt] = __builtin_amdgcn_mfma_f32_16x16x32_bf16(qa[1], k1, S[nt], 0, 0, 0);
        }

        #pragma unroll
        for (int nt = 0; nt < 4; ++nt) {
            #pragma unroll
            for (int r = 0; r < 4; ++r) {
                float pv = __builtin_amdgcn_exp2f(__builtin_fmaf(S[nt][r], c1, -c1));
                lr[r] += pv;
                Ps[wave][quad * 4 + r][nt * 16 + l16] = f2bf_n(pv);
            }
        }
        asm volatile("s_waitcnt lgkmcnt(0)" ::: "memory");
        bf16x8 pa0 = ld_bf16x8(&Ps[wave][l16][quad * 8]);
        bf16x8 pa1 = ld_bf16x8(&Ps[wave][l16][32 + quad * 8]);

        #pragma unroll
        for (int dt = 0; dt < 4; ++dt) {
            bf16x8 v0 = ld_bf16x8(&Vs[dt * 16 + l16][quad * 8]);
            bf16x8 v1 = ld_bf16x8(&Vs[dt * 16 + l16][32 + quad * 8]);
            O[dt] = __builtin_amdgcn_mfma_f32_16x16x32_bf16(pa0, v0, O[dt], 0, 0, 0);
            O[dt] = __builtin_amdgcn_mfma_f32_16x16x32_bf16(pa1, v1, O[dt], 0, 0, 0);
        }
    }

    #pragma unroll
    for (int r = 0; r < 4; ++r) {
        float s = lr[r];
        s += __shfl_xor(s, 1);
        s += __shfl_xor(s, 2);
        s += __shfl_xor(s, 4);
        s += __shfl_xor(s, 8);
        lr[r] = fmaxf(s, 1e-30f);
    }

    #pragma unroll
    for (int r = 0; r < 4; ++r) {
        float inv = 1.f / lr[r];
        size_t row = (size_t)b * NSEQ + q0 + wave * 16 + quad * 4 + r;
        #pragma unroll
        for (int dt = 0; dt < 4; ++dt)
            AO[row * DMODEL + h * DH + dt * 16 + l16] = f2bf_n(O[dt][r] * inv);
    }
}

// ---------- launch ----------
extern "C" void kernel_launch(void* const* d_in, const int* in_sizes, int n_in,
                              void* d_out, int out_size, void* d_ws, size_t ws_size,
                              hipStream_t stream) {
    const float* x    = (const float*)d_in[0];
    const float* wqkv = (const float*)d_in[1];
    const float* bqkv = (const float*)d_in[2];
    const float* wout = (const float*)d_in[3];
    const float* lsc  = (const float*)d_in[4];

    char* ws = (char*)d_ws;
    u16* xb   = (u16*)(ws + 0);           // 16 MB  (dead after qkv_gemm; aliased by AO)
    u16* wqh  = (u16*)(ws + 16777216);    // 6 MB
    u16* wql  = (u16*)(ws + 23068672);    // 6 MB
    u16* wob  = (u16*)(ws + 29360128);    // 2 MB
    u16* qkvb = (u16*)(ws + 31457280);    // 48 MB [8192,3072] bf16
    u16* qn   = (u16*)(ws + 81788928);    // 16 MB [B,H,N,DH]
    u16* kn   = (u16*)(ws + 98566144);    // 16 MB
    u16* vt   = (u16*)(ws + 115343360);   // 16 MB [B,H,DH,N]
    u16* ao   = xb;                       // alias: [8192,1024] bf16

    cvt_bf16<<<MROWS * DMODEL / 256, 256, 0, stream>>>(x, xb, MROWS * DMODEL);
    split_bf16<<<NQKV * DMODEL / 256, 256, 0, stream>>>(wqkv, wqh, wql, NQKV * DMODEL);
    cvt_bf16<<<DMODEL * DMODEL / 256, 256, 0, stream>>>(wout, wob, DMODEL * DMODEL);

    qkv_gemm<<<dim3(MROWS / 128, NQKV / 128), 256, 0, stream>>>(xb, wqh, wql, bqkv, qkvb);
    normalize_qk<<<BATCH * HEADS * NSEQ / 4, 256, 0, stream>>>(qkvb, qn, kn);
    transpose_v<<<dim3(BATCH * HEADS, NSEQ / 64), 256, 0, stream>>>(qkvb, vt);
    flash_attn<<<dim3(BATCH * HEADS, NSEQ / 64), 256, 0, stream>>>(qn, kn, vt, lsc, ao);
    out_gemm<<<dim3(MROWS / 128, DMODEL / 128), 256, 0, stream>>>(ao, wob, (float*)d_out);
}

// Round 7
// 427.661 us; speedup vs baseline: 1.3146x; 1.3146x over previous
//
#include <hip/hip_runtime.h>

// ---------- types ----------
typedef __attribute__((ext_vector_type(8))) __bf16 bf16x8;
typedef __attribute__((ext_vector_type(4))) float f32x4;
typedef unsigned short u16;

__device__ __forceinline__ u16 f2bf(float f) {
    union { float f; unsigned u; } v; v.f = f;
    unsigned r = v.u + 0x7FFFu + ((v.u >> 16) & 1u);
    return (u16)(r >> 16);
}
__device__ __forceinline__ float bf2f(u16 h) {
    union { unsigned u; float f; } v; v.u = ((unsigned)h) << 16;
    return v.f;
}
// native cast: single v_cvt op (RNE)
__device__ __forceinline__ u16 f2bf_n(float f) {
    union { __bf16 b; u16 u; } t; t.b = (__bf16)f; return t.u;
}
__device__ __forceinline__ bf16x8 ld_bf16x8(const u16* p) {
    union { uint4 u; bf16x8 b; } t;
    t.u = *(const uint4*)p;
    return t.b;
}
__device__ __forceinline__ void async16(const void* g, const void* l) {
    __builtin_amdgcn_global_load_lds((const __attribute__((address_space(1))) void*)g,
                                     (__attribute__((address_space(3))) void*)l, 16, 0, 0);
}

// ---------- problem constants ----------
#define BATCH 4
#define NSEQ 2048
#define HEADS 16
#define DH 64
#define DMODEL 1024
#define MROWS 8192   // B*N
#define NQKV 3072

// ---------- elementwise ----------
__global__ void split_bf16(const float* __restrict__ src, u16* __restrict__ hi,
                           u16* __restrict__ lo, int n) {
    int i = blockIdx.x * blockDim.x + threadIdx.x;
    if (i < n) {
        float f = src[i];
        u16 h = f2bf(f);
        hi[i] = h;
        lo[i] = f2bf(f - bf2f(h));
    }
}
__global__ void cvt_bf16(const float* __restrict__ src, u16* __restrict__ dst, int n) {
    int i = blockIdx.x * blockDim.x + threadIdx.x;
    if (i < n) dst[i] = f2bf(src[i]);
}

// ---------- fused QKV GEMM + l2-normalize + V-transpose ----------
// C[m,n] = sum_k A[m,k]*(Bh+Bl)[n,k] + bias[n]; per region:
//   n0 <  1024: q  -> l2-normalize rows per head (wave's 64 cols = exactly 1 head) -> Qn[B,H,N,DH]
//   n0 <  2048: k  -> same -> Kn
//   else      : v  -> write transposed -> Vt[B,H,DH,N] (r-index contiguous in n: ushort4)
// Normalization runs on fp32 accumulators (more accurate than post-bf16 normalize).
__global__ __launch_bounds__(256) void qkv_gemm(
    const u16* __restrict__ A,
    const u16* __restrict__ Bh, const u16* __restrict__ Bl,
    const float* __restrict__ bias,
    u16* __restrict__ Qn, u16* __restrict__ Kn, u16* __restrict__ Vt) {
    const int K = DMODEL, TK = 32;
    __shared__ __align__(16) u16 sA[128 * 32];
    __shared__ __align__(16) u16 sBh[128 * 32], sBl[128 * 32];
    const int tid = threadIdx.x, wave = tid >> 6, lane = tid & 63;
    const int quad = lane >> 4, l16 = lane & 15;
    const int m0 = blockIdx.x * 128, n0 = blockIdx.y * 128;
    const int wm = (wave & 1) * 64, wn = (wave >> 1) * 64;
    f32x4 acc[4][4] = {};

    for (int k0 = 0; k0 < K; k0 += TK) {
        __syncthreads();
        #pragma unroll
        for (int pass = 0; pass < 2; ++pass) {
            const int c = pass * 256 + tid;
            const int row = c >> 2, part = c & 3;
            const int ldsOff = (pass * 256 + wave * 64) * 16;  // bytes; dest = base + lane*16
            const size_t ga = (size_t)(m0 + row) * K + k0 + part * 8;
            const size_t gb = (size_t)(n0 + row) * K + k0 + part * 8;
            async16(A + ga, (const char*)sA + ldsOff);
            async16(Bh + gb, (const char*)sBh + ldsOff);
            async16(Bl + gb, (const char*)sBl + ldsOff);
        }
        __syncthreads();
        bf16x8 a[4];
        #pragma unroll
        for (int mt = 0; mt < 4; ++mt)
            a[mt] = ld_bf16x8(&sA[(wm + mt * 16 + l16) * TK + quad * 8]);
        #pragma unroll
        for (int nt = 0; nt < 4; ++nt) {
            const int cix = wn + nt * 16 + l16;
            bf16x8 bh = ld_bf16x8(&sBh[cix * TK + quad * 8]);
            bf16x8 bl = ld_bf16x8(&sBl[cix * TK + quad * 8]);
            #pragma unroll
            for (int mt = 0; mt < 4; ++mt) {
                acc[mt][nt] = __builtin_amdgcn_mfma_f32_16x16x32_bf16(a[mt], bh, acc[mt][nt], 0, 0, 0);
                acc[mt][nt] = __builtin_amdgcn_mfma_f32_16x16x32_bf16(a[mt], bl, acc[mt][nt], 0, 0, 0);
            }
        }
    }

    // add bias in place (col = n0 + wn + nt*16 + l16)
    #pragma unroll
    for (int nt = 0; nt < 4; ++nt) {
        const float bv = bias[n0 + wn + nt * 16 + l16];
        #pragma unroll
        for (int mt = 0; mt < 4; ++mt)
            #pragma unroll
            for (int r = 0; r < 4; ++r)
                acc[mt][nt][r] += bv;
    }

    if (n0 < 2048) {
        // q or k: wave's 64 cols = one head; d = wn-relative col
        u16* dst = (n0 < 1024) ? Qn : Kn;
        const int nq = (n0 & 1023) + wn;      // position within q (or k) block, = h*64
        const int hh = nq >> 6;               // head
        #pragma unroll
        for (int mt = 0; mt < 4; ++mt) {
            // row sums of squares over the wave's 64 cols
            float ss[4] = {};
            #pragma unroll
            for (int nt = 0; nt < 4; ++nt)
                #pragma unroll
                for (int r = 0; r < 4; ++r)
                    ss[r] += acc[mt][nt][r] * acc[mt][nt][r];
            #pragma unroll
            for (int r = 0; r < 4; ++r) {
                ss[r] += __shfl_xor(ss[r], 1);
                ss[r] += __shfl_xor(ss[r], 2);
                ss[r] += __shfl_xor(ss[r], 4);
                ss[r] += __shfl_xor(ss[r], 8);
                ss[r] = 1.f / fmaxf(sqrtf(ss[r]), 1e-12f);
            }
            const int mbase = m0 + wm + mt * 16 + quad * 4;
            const int b = mbase >> 11, n = mbase & 2047;
            #pragma unroll
            for (int r = 0; r < 4; ++r) {
                size_t rowoff = (((size_t)(b * HEADS + hh)) * NSEQ + n + r) * DH;
                #pragma unroll
                for (int nt = 0; nt < 4; ++nt)
                    dst[rowoff + nt * 16 + l16] = f2bf_n(acc[mt][nt][r] * ss[r]);
            }
        }
    } else {
        // v: write transposed; 4 consecutive n per lane -> ushort4
        const int nv = (n0 - 2048) + wn;
        const int hh = nv >> 6;
        #pragma unroll
        for (int nt = 0; nt < 4; ++nt) {
            const int d = (nv & 63) + nt * 16 + l16;   // 0..63 within head? nv&63==0, so d = nt*16+l16
            #pragma unroll
            for (int mt = 0; mt < 4; ++mt) {
                const int mbase = m0 + wm + mt * 16 + quad * 4;
                const int b = mbase >> 11, n = mbase & 2047;
                ushort4 t;
                t.x = f2bf_n(acc[mt][nt][0]);
                t.y = f2bf_n(acc[mt][nt][1]);
                t.z = f2bf_n(acc[mt][nt][2]);
                t.w = f2bf_n(acc[mt][nt][3]);
                *(ushort4*)&Vt[(((size_t)(b * HEADS + hh)) * DH + d) * NSEQ + n] = t;
            }
        }
    }
}

// ---------- out-proj GEMM: C[m,n] = sum_k A[m,k]*B[n,k], fp32 out ----------
__global__ __launch_bounds__(256) void out_gemm(
    const u16* __restrict__ A, const u16* __restrict__ B, float* __restrict__ C) {
    const int K = DMODEL, N = DMODEL, TK = 32;
    __shared__ __align__(16) u16 sA[128 * 32], sB[128 * 32];
    const int tid = threadIdx.x, wave = tid >> 6, lane = tid & 63;
    const int quad = lane >> 4, l16 = lane & 15;
    const int m0 = blockIdx.x * 128, n0 = blockIdx.y * 128;
    const int wm = (wave & 1) * 64, wn = (wave >> 1) * 64;
    f32x4 acc[4][4] = {};

    for (int k0 = 0; k0 < K; k0 += TK) {
        __syncthreads();
        #pragma unroll
        for (int pass = 0; pass < 2; ++pass) {
            const int c = pass * 256 + tid;
            const int row = c >> 2, part = c & 3;
            const int ldsOff = (pass * 256 + wave * 64) * 16;
            const size_t ga = (size_t)(m0 + row) * K + k0 + part * 8;
            const size_t gb = (size_t)(n0 + row) * K + k0 + part * 8;
            async16(A + ga, (const char*)sA + ldsOff);
            async16(B + gb, (const char*)sB + ldsOff);
        }
        __syncthreads();
        bf16x8 a[4];
        #pragma unroll
        for (int mt = 0; mt < 4; ++mt)
            a[mt] = ld_bf16x8(&sA[(wm + mt * 16 + l16) * TK + quad * 8]);
        #pragma unroll
        for (int nt = 0; nt < 4; ++nt) {
            bf16x8 b = ld_bf16x8(&sB[(wn + nt * 16 + l16) * TK + quad * 8]);
            #pragma unroll
            for (int mt = 0; mt < 4; ++mt)
                acc[mt][nt] = __builtin_amdgcn_mfma_f32_16x16x32_bf16(a[mt], b, acc[mt][nt], 0, 0, 0);
        }
    }
    #pragma unroll
    for (int nt = 0; nt < 4; ++nt) {
        const int n = n0 + wn + nt * 16 + l16;
        #pragma unroll
        for (int mt = 0; mt < 4; ++mt) {
            const int mbase = m0 + wm + mt * 16 + quad * 4;
            #pragma unroll
            for (int r = 0; r < 4; ++r)
                C[(size_t)(mbase + r) * N + n] = acc[mt][nt][r];
        }
    }
}

// ---------- flash attention, cosine specialization (R5 winner, reverted R6 prefetch) ----------
// R4 lesson: lives on wave-level parallelism, don't trade occupancy for per-wave ILP.
// R6 lesson: VGPR prefetch across barriers gets spilled to scratch (WRITE_SIZE 16->838 MB).
__global__ __launch_bounds__(256) void flash_attn(
    const u16* __restrict__ Q, const u16* __restrict__ Kn, const u16* __restrict__ Vt,
    const float* __restrict__ lsc, u16* __restrict__ AO) {
    const int bh = blockIdx.x;
    const int q0 = blockIdx.y * 64;
    const int h = bh & (HEADS - 1), b = bh >> 4;
    const int tid = threadIdx.x, wave = tid >> 6, lane = tid & 63;
    const int quad = lane >> 4, l16 = lane & 15;
    const float scale = __expf(fminf(lsc[h], 4.6051702f));  // ln(100); here = 10
    const float c1 = scale * 1.4426950408889634f;           // scale*log2(e)

    __shared__ __align__(16) u16 Ks[64][72];      // [key][d]
    __shared__ __align__(16) u16 Vs[64][72];      // [d][key]
    __shared__ __align__(16) u16 Ps[4][16][68];   // per-wave P round-trip (C->A layout)

    const u16* qbase = Q + ((size_t)bh * NSEQ + q0 + wave * 16) * DH;
    bf16x8 qa[2];
    qa[0] = ld_bf16x8(qbase + l16 * DH + quad * 8);
    qa[1] = ld_bf16x8(qbase + l16 * DH + 32 + quad * 8);

    f32x4 O[4] = {};
    float lr[4] = {0.f, 0.f, 0.f, 0.f};

    const u16* kb = Kn + (size_t)bh * NSEQ * DH;
    const u16* vb = Vt + (size_t)bh * DH * NSEQ;

    for (int kt = 0; kt < NSEQ; kt += 64) {
        __syncthreads();
        #pragma unroll
        for (int c = tid; c < 512; c += 256) {
            int key = c >> 3, part = c & 7;
            *(uint4*)&Ks[key][part * 8] = *(const uint4*)(kb + (size_t)(kt + key) * DH + part * 8);
        }
        #pragma unroll
        for (int c = tid; c < 512; c += 256) {
            int d = c >> 3, part = c & 7;
            *(uint4*)&Vs[d][part * 8] = *(const uint4*)(vb + (size_t)d * NSEQ + kt + part * 8);
        }
        __syncthreads();

        f32x4 S[4] = {};
        #pragma unroll
        for (int nt = 0; nt < 4; ++nt) {
            bf16x8 k0 = ld_bf16x8(&Ks[nt * 16 + l16][quad * 8]);
            bf16x8 k1 = ld_bf16x8(&Ks[nt * 16 + l16][32 + quad * 8]);
            S[nt] = __builtin_amdgcn_mfma_f32_16x16x32_bf16(qa[0], k0, S[nt], 0, 0, 0);
            S[nt] = __builtin_amdgcn_mfma_f32_16x16x32_bf16(qa[1], k1, S[nt], 0, 0, 0);
        }

        #pragma unroll
        for (int nt = 0; nt < 4; ++nt) {
            #pragma unroll
            for (int r = 0; r < 4; ++r) {
                float pv = __builtin_amdgcn_exp2f(__builtin_fmaf(S[nt][r], c1, -c1));
                lr[r] += pv;
                Ps[wave][quad * 4 + r][nt * 16 + l16] = f2bf_n(pv);
            }
        }
        asm volatile("s_waitcnt lgkmcnt(0)" ::: "memory");
        bf16x8 pa0 = ld_bf16x8(&Ps[wave][l16][quad * 8]);
        bf16x8 pa1 = ld_bf16x8(&Ps[wave][l16][32 + quad * 8]);

        #pragma unroll
        for (int dt = 0; dt < 4; ++dt) {
            bf16x8 v0 = ld_bf16x8(&Vs[dt * 16 + l16][quad * 8]);
            bf16x8 v1 = ld_bf16x8(&Vs[dt * 16 + l16][32 + quad * 8]);
            O[dt] = __builtin_amdgcn_mfma_f32_16x16x32_bf16(pa0, v0, O[dt], 0, 0, 0);
            O[dt] = __builtin_amdgcn_mfma_f32_16x16x32_bf16(pa1, v1, O[dt], 0, 0, 0);
        }
    }

    #pragma unroll
    for (int r = 0; r < 4; ++r) {
        float s = lr[r];
        s += __shfl_xor(s, 1);
        s += __shfl_xor(s, 2);
        s += __shfl_xor(s, 4);
        s += __shfl_xor(s, 8);
        lr[r] = fmaxf(s, 1e-30f);
    }

    #pragma unroll
    for (int r = 0; r < 4; ++r) {
        float inv = 1.f / lr[r];
        size_t row = (size_t)b * NSEQ + q0 + wave * 16 + quad * 4 + r;
        #pragma unroll
        for (int dt = 0; dt < 4; ++dt)
            AO[row * DMODEL + h * DH + dt * 16 + l16] = f2bf_n(O[dt][r] * inv);
    }
}

// ---------- launch ----------
extern "C" void kernel_launch(void* const* d_in, const int* in_sizes, int n_in,
                              void* d_out, int out_size, void* d_ws, size_t ws_size,
                              hipStream_t stream) {
    const float* x    = (const float*)d_in[0];
    const float* wqkv = (const float*)d_in[1];
    const float* bqkv = (const float*)d_in[2];
    const float* wout = (const float*)d_in[3];
    const float* lsc  = (const float*)d_in[4];

    char* ws = (char*)d_ws;
    u16* xb   = (u16*)(ws + 0);           // 16 MB  (dead after qkv_gemm; aliased by AO)
    u16* wqh  = (u16*)(ws + 16777216);    // 6 MB
    u16* wql  = (u16*)(ws + 23068672);    // 6 MB
    u16* wob  = (u16*)(ws + 29360128);    // 2 MB
    u16* qn   = (u16*)(ws + 31457280);    // 16 MB [B,H,N,DH]
    u16* kn   = (u16*)(ws + 48234496);    // 16 MB
    u16* vt   = (u16*)(ws + 65011712);    // 16 MB [B,H,DH,N]
    u16* ao   = xb;                       // alias: [8192,1024] bf16

    cvt_bf16<<<MROWS * DMODEL / 256, 256, 0, stream>>>(x, xb, MROWS * DMODEL);
    split_bf16<<<NQKV * DMODEL / 256, 256, 0, stream>>>(wqkv, wqh, wql, NQKV * DMODEL);
    cvt_bf16<<<DMODEL * DMODEL / 256, 256, 0, stream>>>(wout, wob, DMODEL * DMODEL);

    qkv_gemm<<<dim3(MROWS / 128, NQKV / 128), 256, 0, stream>>>(xb, wqh, wql, bqkv, qn, kn, vt);
    flash_attn<<<dim3(BATCH * HEADS, NSEQ / 64), 256, 0, stream>>>(qn, kn, vt, lsc, ao);
    out_gemm<<<dim3(MROWS / 128, DMODEL / 128), 256, 0, stream>>>(ao, wob, (float*)d_out);
}

// Round 8
// 410.456 us; speedup vs baseline: 1.3697x; 1.0419x over previous
//
#include <hip/hip_runtime.h>

// ---------- types ----------
typedef __attribute__((ext_vector_type(8))) __bf16 bf16x8;
typedef __attribute__((ext_vector_type(4))) float f32x4;
typedef unsigned short u16;

__device__ __forceinline__ u16 f2bf(float f) {
    union { float f; unsigned u; } v; v.f = f;
    unsigned r = v.u + 0x7FFFu + ((v.u >> 16) & 1u);
    return (u16)(r >> 16);
}
__device__ __forceinline__ float bf2f(u16 h) {
    union { unsigned u; float f; } v; v.u = ((unsigned)h) << 16;
    return v.f;
}
// native cast: single v_cvt op (RNE)
__device__ __forceinline__ u16 f2bf_n(float f) {
    union { __bf16 b; u16 u; } t; t.b = (__bf16)f; return t.u;
}
__device__ __forceinline__ bf16x8 ld_bf16x8(const u16* p) {
    union { uint4 u; bf16x8 b; } t;
    t.u = *(const uint4*)p;
    return t.b;
}
__device__ __forceinline__ void async16(const void* g, const void* l) {
    __builtin_amdgcn_global_load_lds((const __attribute__((address_space(1))) void*)g,
                                     (__attribute__((address_space(3))) void*)l, 16, 0, 0);
}

// ---------- problem constants ----------
#define BATCH 4
#define NSEQ 2048
#define HEADS 16
#define DH 64
#define DMODEL 1024
#define MROWS 8192   // B*N
#define NQKV 3072

// ---------- elementwise ----------
__global__ void split_bf16(const float* __restrict__ src, u16* __restrict__ hi,
                           u16* __restrict__ lo, int n) {
    int i = blockIdx.x * blockDim.x + threadIdx.x;
    if (i < n) {
        float f = src[i];
        u16 h = f2bf(f);
        hi[i] = h;
        lo[i] = f2bf(f - bf2f(h));
    }
}
__global__ void cvt_bf16(const float* __restrict__ src, u16* __restrict__ dst, int n) {
    int i = blockIdx.x * blockDim.x + threadIdx.x;
    if (i < n) dst[i] = f2bf(src[i]);
}

// ---------- fused QKV GEMM + l2-normalize + V-transpose (R7 winner, unchanged) ----------
__global__ __launch_bounds__(256) void qkv_gemm(
    const u16* __restrict__ A,
    const u16* __restrict__ Bh, const u16* __restrict__ Bl,
    const float* __restrict__ bias,
    u16* __restrict__ Qn, u16* __restrict__ Kn, u16* __restrict__ Vt) {
    const int K = DMODEL, TK = 32;
    __shared__ __align__(16) u16 sA[128 * 32];
    __shared__ __align__(16) u16 sBh[128 * 32], sBl[128 * 32];
    const int tid = threadIdx.x, wave = tid >> 6, lane = tid & 63;
    const int quad = lane >> 4, l16 = lane & 15;
    const int m0 = blockIdx.x * 128, n0 = blockIdx.y * 128;
    const int wm = (wave & 1) * 64, wn = (wave >> 1) * 64;
    f32x4 acc[4][4] = {};

    for (int k0 = 0; k0 < K; k0 += TK) {
        __syncthreads();
        #pragma unroll
        for (int pass = 0; pass < 2; ++pass) {
            const int c = pass * 256 + tid;
            const int row = c >> 2, part = c & 3;
            const int ldsOff = (pass * 256 + wave * 64) * 16;  // bytes; dest = base + lane*16
            const size_t ga = (size_t)(m0 + row) * K + k0 + part * 8;
            const size_t gb = (size_t)(n0 + row) * K + k0 + part * 8;
            async16(A + ga, (const char*)sA + ldsOff);
            async16(Bh + gb, (const char*)sBh + ldsOff);
            async16(Bl + gb, (const char*)sBl + ldsOff);
        }
        __syncthreads();
        bf16x8 a[4];
        #pragma unroll
        for (int mt = 0; mt < 4; ++mt)
            a[mt] = ld_bf16x8(&sA[(wm + mt * 16 + l16) * TK + quad * 8]);
        #pragma unroll
        for (int nt = 0; nt < 4; ++nt) {
            const int cix = wn + nt * 16 + l16;
            bf16x8 bh = ld_bf16x8(&sBh[cix * TK + quad * 8]);
            bf16x8 bl = ld_bf16x8(&sBl[cix * TK + quad * 8]);
            #pragma unroll
            for (int mt = 0; mt < 4; ++mt) {
                acc[mt][nt] = __builtin_amdgcn_mfma_f32_16x16x32_bf16(a[mt], bh, acc[mt][nt], 0, 0, 0);
                acc[mt][nt] = __builtin_amdgcn_mfma_f32_16x16x32_bf16(a[mt], bl, acc[mt][nt], 0, 0, 0);
            }
        }
    }

    #pragma unroll
    for (int nt = 0; nt < 4; ++nt) {
        const float bv = bias[n0 + wn + nt * 16 + l16];
        #pragma unroll
        for (int mt = 0; mt < 4; ++mt)
            #pragma unroll
            for (int r = 0; r < 4; ++r)
                acc[mt][nt][r] += bv;
    }

    if (n0 < 2048) {
        u16* dst = (n0 < 1024) ? Qn : Kn;
        const int nq = (n0 & 1023) + wn;
        const int hh = nq >> 6;
        #pragma unroll
        for (int mt = 0; mt < 4; ++mt) {
            float ss[4] = {};
            #pragma unroll
            for (int nt = 0; nt < 4; ++nt)
                #pragma unroll
                for (int r = 0; r < 4; ++r)
                    ss[r] += acc[mt][nt][r] * acc[mt][nt][r];
            #pragma unroll
            for (int r = 0; r < 4; ++r) {
                ss[r] += __shfl_xor(ss[r], 1);
                ss[r] += __shfl_xor(ss[r], 2);
                ss[r] += __shfl_xor(ss[r], 4);
                ss[r] += __shfl_xor(ss[r], 8);
                ss[r] = 1.f / fmaxf(sqrtf(ss[r]), 1e-12f);
            }
            const int mbase = m0 + wm + mt * 16 + quad * 4;
            const int b = mbase >> 11, n = mbase & 2047;
            #pragma unroll
            for (int r = 0; r < 4; ++r) {
                size_t rowoff = (((size_t)(b * HEADS + hh)) * NSEQ + n + r) * DH;
                #pragma unroll
                for (int nt = 0; nt < 4; ++nt)
                    dst[rowoff + nt * 16 + l16] = f2bf_n(acc[mt][nt][r] * ss[r]);
            }
        }
    } else {
        const int nv = (n0 - 2048) + wn;
        const int hh = nv >> 6;
        #pragma unroll
        for (int nt = 0; nt < 4; ++nt) {
            const int d = nt * 16 + l16;
            #pragma unroll
            for (int mt = 0; mt < 4; ++mt) {
                const int mbase = m0 + wm + mt * 16 + quad * 4;
                const int b = mbase >> 11, n = mbase & 2047;
                ushort4 t;
                t.x = f2bf_n(acc[mt][nt][0]);
                t.y = f2bf_n(acc[mt][nt][1]);
                t.z = f2bf_n(acc[mt][nt][2]);
                t.w = f2bf_n(acc[mt][nt][3]);
                *(ushort4*)&Vt[(((size_t)(b * HEADS + hh)) * DH + d) * NSEQ + n] = t;
            }
        }
    }
}

// ---------- out-proj GEMM: C[m,n] = sum_k A[m,k]*B[n,k], fp32 out ----------
__global__ __launch_bounds__(256) void out_gemm(
    const u16* __restrict__ A, const u16* __restrict__ B, float* __restrict__ C) {
    const int K = DMODEL, N = DMODEL, TK = 32;
    __shared__ __align__(16) u16 sA[128 * 32], sB[128 * 32];
    const int tid = threadIdx.x, wave = tid >> 6, lane = tid & 63;
    const int quad = lane >> 4, l16 = lane & 15;
    const int m0 = blockIdx.x * 128, n0 = blockIdx.y * 128;
    const int wm = (wave & 1) * 64, wn = (wave >> 1) * 64;
    f32x4 acc[4][4] = {};

    for (int k0 = 0; k0 < K; k0 += TK) {
        __syncthreads();
        #pragma unroll
        for (int pass = 0; pass < 2; ++pass) {
            const int c = pass * 256 + tid;
            const int row = c >> 2, part = c & 3;
            const int ldsOff = (pass * 256 + wave * 64) * 16;
            const size_t ga = (size_t)(m0 + row) * K + k0 + part * 8;
            const size_t gb = (size_t)(n0 + row) * K + k0 + part * 8;
            async16(A + ga, (const char*)sA + ldsOff);
            async16(B + gb, (const char*)sB + ldsOff);
        }
        __syncthreads();
        bf16x8 a[4];
        #pragma unroll
        for (int mt = 0; mt < 4; ++mt)
            a[mt] = ld_bf16x8(&sA[(wm + mt * 16 + l16) * TK + quad * 8]);
        #pragma unroll
        for (int nt = 0; nt < 4; ++nt) {
            bf16x8 b = ld_bf16x8(&sB[(wn + nt * 16 + l16) * TK + quad * 8]);
            #pragma unroll
            for (int mt = 0; mt < 4; ++mt)
                acc[mt][nt] = __builtin_amdgcn_mfma_f32_16x16x32_bf16(a[mt], b, acc[mt][nt], 0, 0, 0);
        }
    }
    #pragma unroll
    for (int nt = 0; nt < 4; ++nt) {
        const int n = n0 + wn + nt * 16 + l16;
        #pragma unroll
        for (int mt = 0; mt < 4; ++mt) {
            const int mbase = m0 + wm + mt * 16 + quad * 4;
            #pragma unroll
            for (int r = 0; r < 4; ++r)
                C[(size_t)(mbase + r) * N + n] = acc[mt][nt][r];
        }
    }
}

// ---------- flash attention, cosine specialization, 8-wave blocks ----------
// R8: 512-thread blocks; 8 waves share one K/V staging (per-wave staging LDS writes
// halve, barriers amortize 2x) while per-wave work stays identical to the R5 winner
// (16 q-rows/wave — R4 showed per-wave growth loses to occupancy). LDS 35.8KB ->
// 4 blocks/CU x 8 waves = 32 waves/CU (100%) vs 47% before. LDS pipe was ~100% busy.
__global__ __launch_bounds__(512) void flash_attn(
    const u16* __restrict__ Q, const u16* __restrict__ Kn, const u16* __restrict__ Vt,
    const float* __restrict__ lsc, u16* __restrict__ AO) {
    const int bh = blockIdx.x;
    const int q0 = blockIdx.y * 128;
    const int h = bh & (HEADS - 1), b = bh >> 4;
    const int tid = threadIdx.x, wave = tid >> 6, lane = tid & 63;
    const int quad = lane >> 4, l16 = lane & 15;
    const float scale = __expf(fminf(lsc[h], 4.6051702f));  // ln(100); here = 10
    const float c1 = scale * 1.4426950408889634f;           // scale*log2(e)

    __shared__ __align__(16) u16 Ks[64][72];      // [key][d]
    __shared__ __align__(16) u16 Vs[64][72];      // [d][key]
    __shared__ __align__(16) u16 Ps[8][16][68];   // per-wave P round-trip (C->A layout)

    const u16* qbase = Q + ((size_t)bh * NSEQ + q0 + wave * 16) * DH;
    bf16x8 qa[2];
    qa[0] = ld_bf16x8(qbase + l16 * DH + quad * 8);
    qa[1] = ld_bf16x8(qbase + l16 * DH + 32 + quad * 8);

    f32x4 O[4] = {};
    float lr[4] = {0.f, 0.f, 0.f, 0.f};

    const u16* kb = Kn + (size_t)bh * NSEQ * DH;
    const u16* vb = Vt + (size_t)bh * DH * NSEQ;

    for (int kt = 0; kt < NSEQ; kt += 64) {
        __syncthreads();
        {   // one uint4 per thread for K, one for V (512 threads cover 64x64 tile each)
            int row = tid >> 3, part = tid & 7;
            *(uint4*)&Ks[row][part * 8] = *(const uint4*)(kb + (size_t)(kt + row) * DH + part * 8);
            *(uint4*)&Vs[row][part * 8] = *(const uint4*)(vb + (size_t)row * NSEQ + kt + part * 8);
        }
        __syncthreads();

        f32x4 S[4] = {};
        #pragma unroll
        for (int nt = 0; nt < 4; ++nt) {
            bf16x8 k0 = ld_bf16x8(&Ks[nt * 16 + l16][quad * 8]);
            bf16x8 k1 = ld_bf16x8(&Ks[nt * 16 + l16][32 + quad * 8]);
            S[nt] = __builtin_amdgcn_mfma_f32_16x16x32_bf16(qa[0], k0, S[nt], 0, 0, 0);
            S[nt] = __builtin_amdgcn_mfma_f32_16x16x32_bf16(qa[1], k1, S[nt], 0, 0, 0);
        }

        #pragma unroll
        for (int nt = 0; nt < 4; ++nt) {
            #pragma unroll
            for (int r = 0; r < 4; ++r) {
                float pv = __builtin_amdgcn_exp2f(__builtin_fmaf(S[nt][r], c1, -c1));
                lr[r] += pv;
                Ps[wave][quad * 4 + r][nt * 16 + l16] = f2bf_n(pv);
            }
        }
        asm volatile("s_waitcnt lgkmcnt(0)" ::: "memory");
        bf16x8 pa0 = ld_bf16x8(&Ps[wave][l16][quad * 8]);
        bf16x8 pa1 = ld_bf16x8(&Ps[wave][l16][32 + quad * 8]);

        #pragma unroll
        for (int dt = 0; dt < 4; ++dt) {
            bf16x8 v0 = ld_bf16x8(&Vs[dt * 16 + l16][quad * 8]);
            bf16x8 v1 = ld_bf16x8(&Vs[dt * 16 + l16][32 + quad * 8]);
            O[dt] = __builtin_amdgcn_mfma_f32_16x16x32_bf16(pa0, v0, O[dt], 0, 0, 0);
            O[dt] = __builtin_amdgcn_mfma_f32_16x16x32_bf16(pa1, v1, O[dt], 0, 0, 0);
        }
    }

    #pragma unroll
    for (int r = 0; r < 4; ++r) {
        float s = lr[r];
        s += __shfl_xor(s, 1);
        s += __shfl_xor(s, 2);
        s += __shfl_xor(s, 4);
        s += __shfl_xor(s, 8);
        lr[r] = fmaxf(s, 1e-30f);
    }

    #pragma unroll
    for (int r = 0; r < 4; ++r) {
        float inv = 1.f / lr[r];
        size_t row = (size_t)b * NSEQ + q0 + wave * 16 + quad * 4 + r;
        #pragma unroll
        for (int dt = 0; dt < 4; ++dt)
            AO[row * DMODEL + h * DH + dt * 16 + l16] = f2bf_n(O[dt][r] * inv);
    }
}

// ---------- launch ----------
extern "C" void kernel_launch(void* const* d_in, const int* in_sizes, int n_in,
                              void* d_out, int out_size, void* d_ws, size_t ws_size,
                              hipStream_t stream) {
    const float* x    = (const float*)d_in[0];
    const float* wqkv = (const float*)d_in[1];
    const float* bqkv = (const float*)d_in[2];
    const float* wout = (const float*)d_in[3];
    const float* lsc  = (const float*)d_in[4];

    char* ws = (char*)d_ws;
    u16* xb   = (u16*)(ws + 0);           // 16 MB  (dead after qkv_gemm; aliased by AO)
    u16* wqh  = (u16*)(ws + 16777216);    // 6 MB
    u16* wql  = (u16*)(ws + 23068672);    // 6 MB
    u16* wob  = (u16*)(ws + 29360128);    // 2 MB
    u16* qn   = (u16*)(ws + 31457280);    // 16 MB [B,H,N,DH]
    u16* kn   = (u16*)(ws + 48234496);    // 16 MB
    u16* vt   = (u16*)(ws + 65011712);    // 16 MB [B,H,DH,N]
    u16* ao   = xb;                       // alias: [8192,1024] bf16

    cvt_bf16<<<MROWS * DMODEL / 256, 256, 0, stream>>>(x, xb, MROWS * DMODEL);
    split_bf16<<<NQKV * DMODEL / 256, 256, 0, stream>>>(wqkv, wqh, wql, NQKV * DMODEL);
    cvt_bf16<<<DMODEL * DMODEL / 256, 256, 0, stream>>>(wout, wob, DMODEL * DMODEL);

    qkv_gemm<<<dim3(MROWS / 128, NQKV / 128), 256, 0, stream>>>(xb, wqh, wql, bqkv, qn, kn, vt);
    flash_attn<<<dim3(BATCH * HEADS, NSEQ / 128), 512, 0, stream>>>(qn, kn, vt, lsc, ao);
    out_gemm<<<dim3(MROWS / 128, DMODEL / 128), 256, 0, stream>>>(ao, wob, (float*)d_out);
}